// Round 3
// baseline (404.657 us; speedup 1.0000x reference)
//
#include <hip/hip_runtime.h>
#include <stdint.h>

#define B_ 8
#define C_ 256
#define N_ 4096
#define M_ 4096
#define NT 128
#define MT 64
#define L2E 1.44269504f

typedef _Float16 f16x8 __attribute__((ext_vector_type(8)));
typedef _Float16 f16x4 __attribute__((ext_vector_type(4)));
typedef float f32x4 __attribute__((ext_vector_type(4)));

__device__ __forceinline__ void async16(const _Float16* g, _Float16* l) {
    __builtin_amdgcn_global_load_lds(
        (const __attribute__((address_space(1))) void*)g,
        (__attribute__((address_space(3))) void*)l, 16, 0, 0);
}

// fused pre-pass: blocks [0,2048) transpose xs -> kt [B,M,C] fp16;
//                 blocks [2048,10240) convert ys -> vb [B,C,M] fp16
__global__ __launch_bounds__(256) void kPre(const float* __restrict__ xs,
                                            const float* __restrict__ ys,
                                            _Float16* __restrict__ kt,
                                            _Float16* __restrict__ vb) {
    int bx = blockIdx.x;
    int t = threadIdx.x;
    if (bx < 2048) {
        __shared__ float tile[64][65];
        int b = bx >> 8, rem = bx & 255;
        int c0 = (rem >> 6) * 64, m0 = (rem & 63) * 64;
        int cl = t >> 4, m4 = (t & 15) * 4;
#pragma unroll
        for (int i = 0; i < 4; i++) {
            int c = c0 + cl + i * 16;
            const float4 v = *(const float4*)(xs + ((size_t)(b * C_ + c) * M_) + m0 + m4);
            tile[m4 + 0][cl + i * 16] = v.x;
            tile[m4 + 1][cl + i * 16] = v.y;
            tile[m4 + 2][cl + i * 16] = v.z;
            tile[m4 + 3][cl + i * 16] = v.w;
        }
        __syncthreads();
        int ml = t >> 4, c4 = (t & 15) * 4;
#pragma unroll
        for (int i = 0; i < 4; i++) {
            int m = m0 + ml + i * 16;
            f16x4 o;
            o[0] = (_Float16)tile[ml + i * 16][c4 + 0];
            o[1] = (_Float16)tile[ml + i * 16][c4 + 1];
            o[2] = (_Float16)tile[ml + i * 16][c4 + 2];
            o[3] = (_Float16)tile[ml + i * 16][c4 + 3];
            *(f16x4*)(kt + ((size_t)(b * M_ + m) * C_) + c0 + c4) = o;
        }
    } else {
        size_t i = ((size_t)(bx - 2048) * 256 + t) * 4;
        float4 v = *(const float4*)(ys + i);
        f16x4 o;
        o[0] = (_Float16)v.x; o[1] = (_Float16)v.y;
        o[2] = (_Float16)v.z; o[3] = (_Float16)v.w;
        *(f16x4*)(vb + i) = o;
    }
}

// Single-barrier pipelined flash attention.
// Per barrier interval (iter it): PV(it-1) [LDS+MFMA] + QK^T(it) [LDS+MFMA] +
// softmax(it) [VALU] + K(it+2) prefetch [async, stays in flight across barrier,
// counted vmcnt(4)]. sK: 3-buffer ring; sP/sAlpha: double-buffered; sFlag: 3-slot.
// PV uses c/n split (wave = 64 channels x 64 n) to halve P re-reads.
__global__ __launch_bounds__(512, 2) void kAttn(const float* __restrict__ h,
                                                const _Float16* __restrict__ kt,
                                                const _Float16* __restrict__ vb,
                                                float* __restrict__ out) {
    __shared__ _Float16 sK3[3][MT * 256];    // 96 KB, rows 256B XOR-swizzled by (row&31)
    __shared__ _Float16 sP[2][NT * 64];      // 32 KB, rows 128B XOR-swizzled by (row&7)
    __shared__ float sAlpha[2][NT];
    __shared__ float sL[NT];
    __shared__ int sFlag[3];

    const int t = threadIdx.x;
    const int w = t >> 6, lane = t & 63, quad = lane >> 4, l15 = lane & 15;
    const int b = blockIdx.x & 7;            // batch -> XCD (L2 residency)
    const int n0 = (blockIdx.x >> 3) * NT;
    const int nb = w * 16;                   // softmax n-strip (16 rows/wave)
    const int cb = (w & 3) * 64;             // PV channel strip (64 ch/wave)
    const int nh = (w >> 2) * 64;            // PV n-half (64 n/wave)

    const _Float16* srcKb = kt + (size_t)b * M_ * C_;
    const _Float16* srcVb = vb + (size_t)b * C_ * M_;

    if (t == 0) { sFlag[0] = 0; sFlag[1] = 0; sFlag[2] = 0; }

    // ---- prologue: issue K0->sK3[0], K1->sK3[1]; stage Q into {sK3[2], sP} ----
    {
#pragma unroll
        for (int j = 0; j < 4; j++) {
            int row = w * 8 + j * 2 + (lane >> 5);
            int logi = (lane & 31) ^ (row & 31);
            async16(srcKb + (size_t)row * C_ + logi * 8, &sK3[0][(w * 8 + j * 2) * 256]);
        }
#pragma unroll
        for (int j = 0; j < 4; j++) {
            int row = w * 8 + j * 2 + (lane >> 5);
            int logi = (lane & 31) ^ (row & 31);
            async16(srcKb + (size_t)(MT + row) * C_ + logi * 8, &sK3[1][(w * 8 + j * 2) * 256]);
        }
        int cl = t >> 4;                 // 0..31 (channel-low)
        int n8 = (t & 15) * 8;           // 0..120 (row base)
        _Float16* qdst = (n8 < 64) ? &sK3[2][0] : &sP[0][0];
        int rbase = (n8 < 64) ? 0 : 64;
#pragma unroll
        for (int i = 0; i < 8; i++) {
            int c = i * 32 + cl;
#pragma unroll
            for (int half = 0; half < 2; half++) {
                const float4 v = *(const float4*)(h + ((size_t)(b * C_ + c) * N_) + n0 + n8 + half * 4);
                float xv[4] = {v.x, v.y, v.z, v.w};
#pragma unroll
                for (int j = 0; j < 4; j++) {
                    int row = n8 + half * 4 + j;
                    qdst[(row - rbase) * 256 + (((c >> 3) ^ (row & 31)) << 3) + (c & 7)] = (_Float16)xv[j];
                }
            }
        }
    }
    asm volatile("s_waitcnt lgkmcnt(0)" ::: "memory");
    __builtin_amdgcn_s_barrier();

    // ---- Q fragments to registers ----
    f16x8 qf[8];
    {
        int qrow = nb + l15;             // wave-uniform region
        const _Float16* qsrc = (qrow < 64) ? &sK3[2][0] : &sP[0][0];
        int rloc = (nb < 64) ? qrow : qrow - 64;
#pragma unroll
        for (int ks = 0; ks < 8; ks++)
            qf[ks] = *(const f16x8*)(&qsrc[rloc * 256 + ((((ks << 2) + quad) ^ (qrow & 31)) << 3)]);
    }
    // qf in regs (lgkm), K0 landed (vmcnt: K1's 4 may remain in flight)
    asm volatile("s_waitcnt lgkmcnt(0) vmcnt(4)" ::: "memory");
    __builtin_amdgcn_s_barrier();

    f32x4 o[4][4];
#pragma unroll
    for (int i = 0; i < 4; i++)
#pragma unroll
        for (int j = 0; j < 4; j++)
            o[i][j] = (f32x4){0.f, 0.f, 0.f, 0.f};

    float mst = -3.0e38f, lp = 0.f;

    // rotating indices: fcur = it%3, fnext = (it+1)%3, fprev = (it-1)%3 == (it+2)%3
    int fprev = 2, fcur = 0, fnext = 1;
    int pp = 0;                          // it & 1

    for (int it = 0; it < M_ / MT; it++) {
        if (t == 0) sFlag[fnext] = 0;    // arm slot for it+1 (last read at it-1: safe)

        // ---- V(it-1) fragments, issued FIRST (oldest vmem) ----
        f16x8 vf[2][4];
        if (it > 0) {
            int m0p = (it - 1) * MT;
#pragma unroll
            for (int ks = 0; ks < 2; ks++)
#pragma unroll
                for (int ct = 0; ct < 4; ct++) {
                    int vrow = cb + ct * 16 + l15;
                    vf[ks][ct] = *(const f16x8*)(srcVb + (size_t)vrow * M_ + m0p + ks * 32 + quad * 8);
                }
        }
        __builtin_amdgcn_sched_barrier(0);   // pin V-issue before K-prefetch

        // ---- K(it+2) prefetch into ring slot fprev ----
        if (it < M_ / MT - 2) {
            const _Float16* srcK = srcKb + (size_t)(it + 2) * MT * C_;
            _Float16* dst = &sK3[fprev][0];
#pragma unroll
            for (int j = 0; j < 4; j++) {
                int row = w * 8 + j * 2 + (lane >> 5);
                int logi = (lane & 31) ^ (row & 31);
                async16(srcK + (size_t)row * C_ + logi * 8, dst + (w * 8 + j * 2) * 256);
            }
        }

        // ---- rescale O by alpha(it-1) before PV(it-1) ----
        if (it > 0 && sFlag[fprev]) {
            float av[4];
#pragma unroll
            for (int nt = 0; nt < 4; nt++) av[nt] = sAlpha[pp ^ 1][nh + nt * 16 + l15];
#pragma unroll
            for (int ct = 0; ct < 4; ct++)
#pragma unroll
                for (int nt = 0; nt < 4; nt++) {
                    o[ct][nt][0] *= av[nt];
                    o[ct][nt][1] *= av[nt];
                    o[ct][nt][2] *= av[nt];
                    o[ct][nt][3] *= av[nt];
                }
        }

        // ---- S^T(it) = K·Q^T : s4[mt][r] = S^T[m=mt*16+quad*4+r][n=nb+l15] ----
        const _Float16* kcur = &sK3[fcur][0];
        f32x4 s4[4];
#pragma unroll
        for (int mt = 0; mt < 4; mt++) s4[mt] = (f32x4){0.f, 0.f, 0.f, 0.f};
        __builtin_amdgcn_s_setprio(1);
#pragma unroll
        for (int ks = 0; ks < 8; ks++) {
#pragma unroll
            for (int mt = 0; mt < 4; mt++) {
                int krow = mt * 16 + l15;
                f16x8 bk = *(const f16x8*)(&kcur[krow * 256 + ((((ks << 2) + quad) ^ (krow & 31)) << 3)]);
                s4[mt] = __builtin_amdgcn_mfma_f32_16x16x32_f16(bk, qf[ks], s4[mt], 0, 0, 0);
            }
        }
        __builtin_amdgcn_s_setprio(0);

        // ---- PV(it-1): O += V·P^T (interleaves with softmax below) ----
        if (it > 0) {
            const _Float16* pprev = &sP[pp ^ 1][0];
            __builtin_amdgcn_s_setprio(1);
#pragma unroll
            for (int ks = 0; ks < 2; ks++) {
#pragma unroll
                for (int nt = 0; nt < 4; nt++) {
                    int prow = nh + nt * 16 + l15;
                    f16x8 bp = *(const f16x8*)(&pprev[prow * 64 + ((((ks << 2) + quad) ^ (prow & 7)) << 3)]);
#pragma unroll
                    for (int ct = 0; ct < 4; ct++)
                        o[ct][nt] = __builtin_amdgcn_mfma_f32_16x16x32_f16(vf[ks][ct], bp, o[ct][nt], 0, 0, 0);
                }
            }
            __builtin_amdgcn_s_setprio(0);
        }

        // ---- softmax(it) on this lane's row n = nb+l15 ----
        float rowmax = fmaxf(fmaxf(fmaxf(s4[0][0], s4[0][1]), fmaxf(s4[0][2], s4[0][3])),
                             fmaxf(fmaxf(s4[1][0], s4[1][1]), fmaxf(s4[1][2], s4[1][3])));
        rowmax = fmaxf(rowmax, fmaxf(fmaxf(fmaxf(s4[2][0], s4[2][1]), fmaxf(s4[2][2], s4[2][3])),
                                     fmaxf(fmaxf(s4[3][0], s4[3][1]), fmaxf(s4[3][2], s4[3][3]))));
        rowmax = fmaxf(rowmax, __shfl_xor(rowmax, 16, 64));
        rowmax = fmaxf(rowmax, __shfl_xor(rowmax, 32, 64));
        float al = 1.0f;
        if (rowmax > mst) {
            al = exp2f((mst - rowmax) * L2E);
            mst = rowmax;
        }
        const float mb = mst * L2E;
        float psum = 0.f;
#pragma unroll
        for (int mt = 0; mt < 4; mt++)
#pragma unroll
            for (int r = 0; r < 4; r++) {
                float p = exp2f(s4[mt][r] * L2E - mb);
                s4[mt][r] = p;
                psum += p;
            }
        lp = lp * al + psum;
        if (quad == 0) {
            sAlpha[pp][nb + l15] = al;
            if (al != 1.0f) atomicOr(&sFlag[fcur], 1);
        }

        // ---- P(it) -> sP[pp], swizzled b64 writes ----
        {
            int prow = nb + l15;
            _Float16* pdst = &sP[pp][0];
#pragma unroll
            for (int mt = 0; mt < 4; mt++) {
                f16x4 pk;
                pk[0] = (_Float16)s4[mt][0];
                pk[1] = (_Float16)s4[mt][1];
                pk[2] = (_Float16)s4[mt][2];
                pk[3] = (_Float16)s4[mt][3];
                *(f16x4*)(&pdst[prow * 64 + ((((mt << 1) + (quad >> 1)) ^ (prow & 7)) << 3) + ((quad & 1) << 2)]) = pk;
            }
        }

        // ---- single barrier: P/alpha/flag visible; K(it+1) landed; K(it+2) in flight ----
        asm volatile("s_waitcnt lgkmcnt(0)" ::: "memory");
        if (it < M_ / MT - 2) asm volatile("s_waitcnt vmcnt(4)" ::: "memory");
        else                  asm volatile("s_waitcnt vmcnt(0)" ::: "memory");
        __builtin_amdgcn_s_barrier();

        // rotate ring indices
        int tmp = fprev; fprev = fcur; fcur = fnext; fnext = tmp;
        pp ^= 1;
    }

    // ---- epilogue: rescale by alpha(63), PV(63), normalize, store ----
    {
        if (sFlag[fprev]) {
            float av[4];
#pragma unroll
            for (int nt = 0; nt < 4; nt++) av[nt] = sAlpha[pp ^ 1][nh + nt * 16 + l15];
#pragma unroll
            for (int ct = 0; ct < 4; ct++)
#pragma unroll
                for (int nt = 0; nt < 4; nt++) {
                    o[ct][nt][0] *= av[nt];
                    o[ct][nt][1] *= av[nt];
                    o[ct][nt][2] *= av[nt];
                    o[ct][nt][3] *= av[nt];
                }
        }
        f16x8 vf[2][4];
        int m0p = (M_ / MT - 1) * MT;
#pragma unroll
        for (int ks = 0; ks < 2; ks++)
#pragma unroll
            for (int ct = 0; ct < 4; ct++) {
                int vrow = cb + ct * 16 + l15;
                vf[ks][ct] = *(const f16x8*)(srcVb + (size_t)vrow * M_ + m0p + ks * 32 + quad * 8);
            }
        const _Float16* pprev = &sP[pp ^ 1][0];
#pragma unroll
        for (int ks = 0; ks < 2; ks++) {
#pragma unroll
            for (int nt = 0; nt < 4; nt++) {
                int prow = nh + nt * 16 + l15;
                f16x8 bp = *(const f16x8*)(&pprev[prow * 64 + ((((ks << 2) + quad) ^ (prow & 7)) << 3)]);
#pragma unroll
                for (int ct = 0; ct < 4; ct++)
                    o[ct][nt] = __builtin_amdgcn_mfma_f32_16x16x32_f16(vf[ks][ct], bp, o[ct][nt], 0, 0, 0);
            }
        }
    }

    lp += __shfl_xor(lp, 16, 64);
    lp += __shfl_xor(lp, 32, 64);
    if (quad == 0) sL[nb + l15] = lp;
    __syncthreads();
    float linv[4];
#pragma unroll
    for (int nt = 0; nt < 4; nt++) linv[nt] = 1.0f / sL[nh + nt * 16 + l15];
#pragma unroll
    for (int ct = 0; ct < 4; ct++)
#pragma unroll
        for (int nt = 0; nt < 4; nt++)
#pragma unroll
            for (int r = 0; r < 4; r++) {
                int c = cb + ct * 16 + quad * 4 + r;
                out[((size_t)(b * C_ + c)) * N_ + n0 + nh + nt * 16 + l15] = o[ct][nt][r] * linv[nt];
            }
}

extern "C" void kernel_launch(void* const* d_in, const int* in_sizes, int n_in,
                              void* d_out, int out_size, void* d_ws, size_t ws_size,
                              hipStream_t stream) {
    const float* h  = (const float*)d_in[0];
    const float* xs = (const float*)d_in[1];
    const float* ys = (const float*)d_in[2];
    float* out = (float*)d_out;

    _Float16* kt  = (_Float16*)d_ws;                    // [B,M,C] fp16: 16 MB
    _Float16* vbb = kt + (size_t)B_ * M_ * C_;          // [B,C,M] fp16: 16 MB

    kPre<<<dim3(2048 + 8192), 256, 0, stream>>>(xs, ys, kt, vbb);
    kAttn<<<dim3(B_ * (N_ / NT)), 512, 0, stream>>>(h, kt, vbb, out);
}